// Round 21
// baseline (17.998 us; speedup 1.0000x reference)
//
#include <hip/hip_runtime.h>

#define NS 8192
#define MS 2048
#define DD 32
#define MSPLIT 16
#define MCH 128       // m per block
#define NIT32 4       // 32-row m-tiles per block
#define RBLK 32       // reduce blocks

typedef __attribute__((ext_vector_type(8))) short bf16x8;
typedef __attribute__((ext_vector_type(4))) float f32x4;
typedef __attribute__((ext_vector_type(16))) float f32x16;
typedef unsigned short u16;
typedef unsigned int u32;

// ws byte offsets
#define PART_OFF 0                          // [MSPLIT][NS] f32 (512 KB)
#define MM_OFF   (MSPLIT * NS * 4)          // 2 u32 (min,max bits)
#define CNT_OFF  (MM_OFF + 8)               // 1 u32

__device__ inline float fast_exp2(float x) {
#if __has_builtin(__builtin_amdgcn_exp2f)
    return __builtin_amdgcn_exp2f(x);
#else
    return exp2f(x);
#endif
}
__device__ inline float fast_rcp(float x) {
#if __has_builtin(__builtin_amdgcn_rcpf)
    return __builtin_amdgcn_rcpf(x);
#else
    return 1.0f / x;
#endif
}

__device__ inline u32 cvt_pk_bf16(float a, float b) {
    u32 r;
    asm("v_cvt_pk_bf16_f32 %0, %1, %2" : "=v"(r) : "v"(a), "v"(b));
    return r;
}

// Split 8 floats into hi/lo bf16x8 (RNE). Pack-order safe: W and X use the
// same helper, so MFMA dots pair identical k-elements either way.
__device__ inline void split8(const float* v, bf16x8& hi, bf16x8& lo) {
    union { u32 u[4]; bf16x8 b; } H, L;
#pragma unroll
    for (int j = 0; j < 4; ++j) {
        u32 h = cvt_pk_bf16(v[2 * j], v[2 * j + 1]);
        float ha = __uint_as_float(h << 16);
        float hb = __uint_as_float(h & 0xFFFF0000u);
        L.u[j] = cvt_pk_bf16(v[2 * j] - ha, v[2 * j + 1] - hb);
        H.u[j] = h;
    }
    hi = H.b;
    lo = L.b;
}

// R20 structure moved to 32x32x16 MFMA (µbench: +15% rate vs 16x16, and half
// the MFMA instruction count). A = W (m on rows, R19-validated direction),
// B = X. Fragment mapping analogous to the validated 16x16 one:
//   A/B: index = lane&31, k_local = (lane>>5)*8 + j   (within a K=16 chunk)
//   D:   col = lane&31 (n), row = (reg&3) + 8*(reg>>2) + 4*(lane>>5) (m)
// Per (32m x 32n) tile: 12 MFMAs = 3 hi/lo products x 2 k-chunks x {B,C}.
__global__ __launch_bounds__(256, 2) void kde_fused(const float* __restrict__ samples,
                                                    const float* __restrict__ means,
                                                    const float* __restrict__ stds,
                                                    unsigned char* __restrict__ wsb) {
    // fragment-order W: [it][c][h5][r31][8] u16 ; 4 arrays x 8 KB = 32 KB
    __shared__ u16 WBH[4096], WBL[4096], WCH[4096], WCL[4096];
    __shared__ float A2s[MCH];

    const int t = threadIdx.x;
    const int m0 = blockIdx.y * MCH;
    const float L2E = 1.4426950408889634f;

    if (blockIdx.x == 0 && blockIdx.y == 0 && t == 0) {
        unsigned* mm = (unsigned*)(wsb + MM_OFF);
        mm[0] = 0x7f7fffffu;  // FLT_MAX bits (uint cmp == float cmp, all positive)
        mm[1] = 0u;
        *(unsigned*)(wsb + CNT_OFF) = 0u;
    }

    // ---- phase 1: W chunk -> LDS, one thread per (m_local, 16-d chunk c) ----
    {
        const int ml = t >> 1, c = t & 1;    // c = k-chunk (d 16c..16c+15)
        const float* mp = means + (size_t)(m0 + ml) * DD + c * 16;
        const float* vp = stds  + (size_t)(m0 + ml) * DD + c * 16;
        float mu[16], sd[16];
#pragma unroll
        for (int j = 0; j < 4; ++j) {
            float4 a4 = *(const float4*)(mp + j * 4);
            float4 c4 = *(const float4*)(vp + j * 4);
            mu[j*4+0]=a4.x; mu[j*4+1]=a4.y; mu[j*4+2]=a4.z; mu[j*4+3]=a4.w;
            sd[j*4+0]=c4.x; sd[j*4+1]=c4.y; sd[j*4+2]=c4.z; sd[j*4+3]=c4.w;
        }
        float Bv[16], Cv[16], a = 0.f;
#pragma unroll
        for (int j = 0; j < 16; ++j) {
            float inv = fast_rcp(sd[j]);
            Bv[j] = L2E * mu[j] * inv;
            Cv[j] = -0.5f * L2E * inv;
            a += mu[j] * mu[j] * inv;
        }
        a += __shfl_xor(a, 1);   // combine the two 16-d chunks of row ml
        if (c == 0) A2s[ml] = -0.5f * L2E * a - 11.0f;  // -log2(M) folds the mean

        const int it = ml >> 5, r31 = ml & 31;
#pragma unroll
        for (int h5 = 0; h5 < 2; ++h5) {
            bf16x8 bh, bl, ch, cl;
            split8(Bv + h5 * 8, bh, bl);
            split8(Cv + h5 * 8, ch, cl);
            const int base = (((it * 2 + c) * 2 + h5) * 32 + r31) * 8;
            *(bf16x8*)&WBH[base] = bh;
            *(bf16x8*)&WBL[base] = bl;
            *(bf16x8*)&WCH[base] = ch;
            *(bf16x8*)&WCL[base] = cl;
        }
    }

    // ---- phase 2: X fragments straight from samples ----
    const int lane = t & 63, wid = t >> 6;
    const int r31 = lane & 31, h5 = lane >> 5;
    const int n0w = blockIdx.x * 256 + wid * 64;

    bf16x8 xh[2][2], xl[2][2], qh[2][2], ql[2][2];   // [nt][c]
#pragma unroll
    for (int nt = 0; nt < 2; ++nt) {
        const float* sp = samples + (size_t)(n0w + nt * 32 + r31) * DD;
#pragma unroll
        for (int c = 0; c < 2; ++c) {
            const float* p = sp + c * 16 + h5 * 8;
            float4 a4 = *(const float4*)p, b4 = *(const float4*)(p + 4);
            float xv[8] = {a4.x, a4.y, a4.z, a4.w, b4.x, b4.y, b4.z, b4.w};
            float qv[8];
#pragma unroll
            for (int j = 0; j < 8; ++j) qv[j] = xv[j] * xv[j];
            split8(xv, xh[nt][c], xl[nt][c]);
            split8(qv, qh[nt][c], ql[nt][c]);
        }
    }

    __syncthreads();

    // ---- phase 3: m-loop, D = W·X (m on rows), 32x32x16 ----
    float rs[2] = {0.f, 0.f};

#pragma unroll 2
    for (int it = 0; it < NIT32; ++it) {
        bf16x8 wbh[2], wch[2], wbl[2], wcl[2];
#pragma unroll
        for (int c = 0; c < 2; ++c) {
            const int base = (((it * 2 + c) * 2 + h5) * 32 + r31) * 8;
            wbh[c] = *(const bf16x8*)&WBH[base];
            wch[c] = *(const bf16x8*)&WCH[base];
            wbl[c] = *(const bf16x8*)&WBL[base];
            wcl[c] = *(const bf16x8*)&WCL[base];
        }
        // a2 rows for reg r = p*4+q: row = q + 8p + 4*h5
        f32x4 a2v[4];
#pragma unroll
        for (int p = 0; p < 4; ++p)
            a2v[p] = *(const f32x4*)&A2s[it * 32 + p * 8 + h5 * 4];

#pragma unroll
        for (int nt = 0; nt < 2; ++nt) {
            f32x16 acc;
#pragma unroll
            for (int p = 0; p < 4; ++p)
#pragma unroll
                for (int q = 0; q < 4; ++q) acc[p * 4 + q] = a2v[p][q];

            acc = __builtin_amdgcn_mfma_f32_32x32x16_bf16(wbh[0], xh[nt][0], acc, 0, 0, 0);
            acc = __builtin_amdgcn_mfma_f32_32x32x16_bf16(wbh[1], xh[nt][1], acc, 0, 0, 0);
            acc = __builtin_amdgcn_mfma_f32_32x32x16_bf16(wch[0], qh[nt][0], acc, 0, 0, 0);
            acc = __builtin_amdgcn_mfma_f32_32x32x16_bf16(wch[1], qh[nt][1], acc, 0, 0, 0);
            acc = __builtin_amdgcn_mfma_f32_32x32x16_bf16(wbh[0], xl[nt][0], acc, 0, 0, 0);
            acc = __builtin_amdgcn_mfma_f32_32x32x16_bf16(wbh[1], xl[nt][1], acc, 0, 0, 0);
            acc = __builtin_amdgcn_mfma_f32_32x32x16_bf16(wch[0], ql[nt][0], acc, 0, 0, 0);
            acc = __builtin_amdgcn_mfma_f32_32x32x16_bf16(wch[1], ql[nt][1], acc, 0, 0, 0);
            acc = __builtin_amdgcn_mfma_f32_32x32x16_bf16(wbl[0], xh[nt][0], acc, 0, 0, 0);
            acc = __builtin_amdgcn_mfma_f32_32x32x16_bf16(wbl[1], xh[nt][1], acc, 0, 0, 0);
            acc = __builtin_amdgcn_mfma_f32_32x32x16_bf16(wcl[0], qh[nt][0], acc, 0, 0, 0);
            acc = __builtin_amdgcn_mfma_f32_32x32x16_bf16(wcl[1], qh[nt][1], acc, 0, 0, 0);

            float e[16];
#pragma unroll
            for (int r = 0; r < 16; ++r) e[r] = fast_exp2(acc[r]);
            rs[nt] += (((e[0] + e[1]) + (e[2] + e[3])) +
                       ((e[4] + e[5]) + (e[6] + e[7]))) +
                      (((e[8] + e[9]) + (e[10] + e[11])) +
                       ((e[12] + e[13]) + (e[14] + e[15])));
        }
    }

    // combine the two lane-halves (rows 4h5+... cover complementary m)
#pragma unroll
    for (int nt = 0; nt < 2; ++nt) rs[nt] += __shfl_xor(rs[nt], 32);

    float* partial = (float*)(wsb + PART_OFF);
    if (h5 == 0) {   // lanes 0..31: n = n0w + nt*32 + r31, 128B coalesced
#pragma unroll
        for (int nt = 0; nt < 2; ++nt)
            partial[(size_t)blockIdx.y * NS + n0w + nt * 32 + r31] = rs[nt];
    }
}

// Merged reduce+flip (R16, proven): 32 co-resident blocks; dist in registers;
// min/max atomics; counter rendezvous (cnt initialized by kde_fused, ordered
// by the kernel boundary); distributed flip.
__global__ __launch_bounds__(256) void reduce_flip(unsigned char* __restrict__ wsb,
                                                   float* __restrict__ out) {
    const float* partial = (const float*)(wsb + PART_OFF);
    unsigned* mm = (unsigned*)(wsb + MM_OFF);
    unsigned* cnt = (unsigned*)(wsb + CNT_OFF);

    const int tid = threadIdx.x;
    const int n = blockIdx.x * 256 + tid;
    float v = 0.f;
#pragma unroll
    for (int j = 0; j < MSPLIT; ++j) v += partial[(size_t)j * NS + n];

    float mn = v, mx = v;
#pragma unroll
    for (int o = 1; o < 64; o <<= 1) {
        mn = fminf(mn, __shfl_xor(mn, o));
        mx = fmaxf(mx, __shfl_xor(mx, o));
    }
    __shared__ float smn[4], smx[4];
    __shared__ float sres[2];
    const int wv = tid >> 6, ln = tid & 63;
    if (ln == 0) { smn[wv] = mn; smx[wv] = mx; }
    __syncthreads();
    if (tid == 0) {
#pragma unroll
        for (int j = 1; j < 4; ++j) {
            mn = fminf(mn, smn[j]);
            mx = fmaxf(mx, smx[j]);
        }
        atomicMin(mm + 0, __float_as_uint(mn));
        atomicMax(mm + 1, __float_as_uint(mx));
        __threadfence();                       // release our atomics
        atomicAdd(cnt, 1u);
        while (__hip_atomic_load(cnt, __ATOMIC_ACQUIRE, __HIP_MEMORY_SCOPE_AGENT)
               < RBLK) {}
        sres[0] = __uint_as_float(
            __hip_atomic_load(mm + 0, __ATOMIC_RELAXED, __HIP_MEMORY_SCOPE_AGENT));
        sres[1] = __uint_as_float(
            __hip_atomic_load(mm + 1, __ATOMIC_RELAXED, __HIP_MEMORY_SCOPE_AGENT));
    }
    __syncthreads();
    out[n] = sres[1] + sres[0] - v;
}

extern "C" void kernel_launch(void* const* d_in, const int* in_sizes, int n_in,
                              void* d_out, int out_size, void* d_ws, size_t ws_size,
                              hipStream_t stream) {
    const float* samples = (const float*)d_in[0];
    const float* means   = (const float*)d_in[1];
    const float* stds    = (const float*)d_in[2];
    unsigned char* ws = (unsigned char*)d_ws;
    float* out = (float*)d_out;

    kde_fused<<<dim3(NS / 256, MSPLIT), 256, 0, stream>>>(samples, means, stds, ws);
    reduce_flip<<<dim3(RBLK), 256, 0, stream>>>(ws, out);
}

// Round 22
// 16.851 us; speedup vs baseline: 1.0681x; 1.0681x over previous
//
#include <hip/hip_runtime.h>

#define NS 8192
#define MS 2048
#define DD 32
#define MSPLIT 16
#define MCH 128       // m per block
#define NITS 8        // m-tiles per block
#define RBLK 32       // reduce blocks

typedef __attribute__((ext_vector_type(8))) short bf16x8;
typedef __attribute__((ext_vector_type(4))) float f32x4;
typedef unsigned short u16;
typedef unsigned int u32;

// ws byte offsets
#define PART_OFF 0                          // [MSPLIT][NS] f32 (512 KB)
#define MM_OFF   (MSPLIT * NS * 4)          // 2 u32 (min,max bits)
#define CNT_OFF  (MM_OFF + 8)               // 1 u32

__device__ inline float fast_exp2(float x) {
#if __has_builtin(__builtin_amdgcn_exp2f)
    return __builtin_amdgcn_exp2f(x);
#else
    return exp2f(x);
#endif
}
__device__ inline float fast_rcp(float x) {
#if __has_builtin(__builtin_amdgcn_rcpf)
    return __builtin_amdgcn_rcpf(x);
#else
    return 1.0f / x;
#endif
}

__device__ inline u32 cvt_pk_bf16(float a, float b) {
    u32 r;
    asm("v_cvt_pk_bf16_f32 %0, %1, %2" : "=v"(r) : "v"(a), "v"(b));
    return r;
}

// hi-only pack (for W: lo term dropped this round — see error budget above)
__device__ inline bf16x8 pack8(const float* v) {
    union { u32 u[4]; bf16x8 b; } H;
#pragma unroll
    for (int j = 0; j < 4; ++j) H.u[j] = cvt_pk_bf16(v[2 * j], v[2 * j + 1]);
    return H.b;
}

// Split 8 floats into hi/lo bf16x8 (RNE) — still used for X.
__device__ inline void split8(const float* v, bf16x8& hi, bf16x8& lo) {
    union { u32 u[4]; bf16x8 b; } H, L;
#pragma unroll
    for (int j = 0; j < 4; ++j) {
        u32 h = cvt_pk_bf16(v[2 * j], v[2 * j + 1]);
        float ha = __uint_as_float(h << 16);
        float hb = __uint_as_float(h & 0xFFFF0000u);
        L.u[j] = cvt_pk_bf16(v[2 * j] - ha, v[2 * j + 1] - hb);
        H.u[j] = h;
    }
    hi = H.b;
    lo = L.b;
}

// R20 body (proven 17.14us) with the two W_lo MFMA products DROPPED:
// products now {xh*Bh, qh*Ch, xl*Bh, ql*Ch}. First-order W-rounding error
// ~0.5% relative on dist (~1e-8 abs) vs 2% threshold — trades 5000x accuracy
// margin for a 33% MFMA-work cut on the MFMA-bound main loop. Also deletes
// W_lo conversion VALU, 16 KB LDS, and 2 ds_reads per it.
__global__ __launch_bounds__(256, 4) void kde_fused(const float* __restrict__ samples,
                                                    const float* __restrict__ means,
                                                    const float* __restrict__ stds,
                                                    unsigned char* __restrict__ wsb) {
    __shared__ u16 WBH[NITS * 512], WCH[NITS * 512];   // [it][qd][r15][8]
    __shared__ float A2s[MCH];

    const int t = threadIdx.x;
    const int m0 = blockIdx.y * MCH;
    const float L2E = 1.4426950408889634f;

    if (blockIdx.x == 0 && blockIdx.y == 0 && t == 0) {
        unsigned* mm = (unsigned*)(wsb + MM_OFF);
        mm[0] = 0x7f7fffffu;  // FLT_MAX bits (uint cmp == float cmp, all positive)
        mm[1] = 0u;
        *(unsigned*)(wsb + CNT_OFF) = 0u;
    }

    // ---- phase 1: W chunk -> LDS (hi only), one thread per (m_local, 16-d half) ----
    {
        const int ml = t >> 1, half = t & 1, d0 = half * 16;
        const float* mp = means + (size_t)(m0 + ml) * DD + d0;
        const float* vp = stds  + (size_t)(m0 + ml) * DD + d0;
        float mu[16], sd[16];
#pragma unroll
        for (int j = 0; j < 4; ++j) {
            float4 a4 = *(const float4*)(mp + j * 4);
            float4 c4 = *(const float4*)(vp + j * 4);
            mu[j*4+0]=a4.x; mu[j*4+1]=a4.y; mu[j*4+2]=a4.z; mu[j*4+3]=a4.w;
            sd[j*4+0]=c4.x; sd[j*4+1]=c4.y; sd[j*4+2]=c4.z; sd[j*4+3]=c4.w;
        }
        float Bv[16], Cv[16], a = 0.f;
#pragma unroll
        for (int j = 0; j < 16; ++j) {
            float inv = fast_rcp(sd[j]);
            Bv[j] = L2E * mu[j] * inv;
            Cv[j] = -0.5f * L2E * inv;
            a += mu[j] * mu[j] * inv;
        }
        a += __shfl_xor(a, 1);   // combine the two 16-d halves of row ml
        if (half == 0) A2s[ml] = -0.5f * L2E * a - 11.0f;  // -log2(M) folds mean

        const int it = ml >> 4, r15 = ml & 15;
#pragma unroll
        for (int r2 = 0; r2 < 2; ++r2) {
            const int qd = half * 2 + r2;
            const int base = ((it * 4 + qd) * 16 + r15) * 8;
            *(bf16x8*)&WBH[base] = pack8(Bv + r2 * 8);
            *(bf16x8*)&WCH[base] = pack8(Cv + r2 * 8);
        }
    }

    // ---- phase 2: X fragments straight from samples (all 4 tiles up front) ----
    const int lane = t & 63, wid = t >> 6;
    const int r15 = lane & 15, g = lane >> 4;
    const int n0 = blockIdx.x * 256 + wid * 64;

    bf16x8 xh[4], xl[4], qh[4], ql[4];
#pragma unroll
    for (int nt = 0; nt < 4; ++nt) {
        const float* sp = samples + (size_t)(n0 + nt * 16 + r15) * DD + g * 8;
        float4 a4 = *(const float4*)sp, b4 = *(const float4*)(sp + 4);
        float xv[8] = {a4.x, a4.y, a4.z, a4.w, b4.x, b4.y, b4.z, b4.w};
        float qv[8];
#pragma unroll
        for (int j = 0; j < 8; ++j) qv[j] = xv[j] * xv[j];
        split8(xv, xh[nt], xl[nt]);
        split8(qv, qh[nt], ql[nt]);
    }

    __syncthreads();

    // ---- phase 3: m-loop, D = W·X (m on rows), 4 MFMAs per tile ----
    float rs[4] = {0.f, 0.f, 0.f, 0.f};

#pragma unroll 2
    for (int it = 0; it < NITS; ++it) {
        const int base = ((it * 4 + g) * 16 + r15) * 8;
        bf16x8 bh = *(const bf16x8*)&WBH[base];
        bf16x8 ch = *(const bf16x8*)&WCH[base];
        // rows of this lane are m = it*16 + g*4 + r  ->  16B-aligned f32x4
        const f32x4 a2v = *(const f32x4*)&A2s[it * 16 + g * 4];
#pragma unroll
        for (int nt = 0; nt < 4; ++nt) {
            f32x4 acc = a2v;
            acc = __builtin_amdgcn_mfma_f32_16x16x32_bf16(bh, xh[nt], acc, 0, 0, 0);
            acc = __builtin_amdgcn_mfma_f32_16x16x32_bf16(ch, qh[nt], acc, 0, 0, 0);
            acc = __builtin_amdgcn_mfma_f32_16x16x32_bf16(bh, xl[nt], acc, 0, 0, 0);
            acc = __builtin_amdgcn_mfma_f32_16x16x32_bf16(ch, ql[nt], acc, 0, 0, 0);
            rs[nt] += (fast_exp2(acc[0]) + fast_exp2(acc[1]))
                    + (fast_exp2(acc[2]) + fast_exp2(acc[3]));
        }
    }

    // sum the 4 g-groups (m-row blocks): 2 shfl steps
#pragma unroll
    for (int nt = 0; nt < 4; ++nt) {
        rs[nt] += __shfl_xor(rs[nt], 16);
        rs[nt] += __shfl_xor(rs[nt], 32);
    }

    float* partial = (float*)(wsb + PART_OFF);
    if (g == 0) {   // lanes 0..15: n = n0 + nt*16 + r15, 64B coalesced per nt
#pragma unroll
        for (int nt = 0; nt < 4; ++nt)
            partial[(size_t)blockIdx.y * NS + n0 + nt * 16 + r15] = rs[nt];
    }
}

// Merged reduce+flip (R16, proven): 32 co-resident blocks; dist in registers;
// min/max atomics; counter rendezvous (cnt initialized by kde_fused, ordered
// by the kernel boundary); distributed flip.
__global__ __launch_bounds__(256) void reduce_flip(unsigned char* __restrict__ wsb,
                                                   float* __restrict__ out) {
    const float* partial = (const float*)(wsb + PART_OFF);
    unsigned* mm = (unsigned*)(wsb + MM_OFF);
    unsigned* cnt = (unsigned*)(wsb + CNT_OFF);

    const int tid = threadIdx.x;
    const int n = blockIdx.x * 256 + tid;
    float v = 0.f;
#pragma unroll
    for (int j = 0; j < MSPLIT; ++j) v += partial[(size_t)j * NS + n];

    float mn = v, mx = v;
#pragma unroll
    for (int o = 1; o < 64; o <<= 1) {
        mn = fminf(mn, __shfl_xor(mn, o));
        mx = fmaxf(mx, __shfl_xor(mx, o));
    }
    __shared__ float smn[4], smx[4];
    __shared__ float sres[2];
    const int wv = tid >> 6, ln = tid & 63;
    if (ln == 0) { smn[wv] = mn; smx[wv] = mx; }
    __syncthreads();
    if (tid == 0) {
#pragma unroll
        for (int j = 1; j < 4; ++j) {
            mn = fminf(mn, smn[j]);
            mx = fmaxf(mx, smx[j]);
        }
        atomicMin(mm + 0, __float_as_uint(mn));
        atomicMax(mm + 1, __float_as_uint(mx));
        __threadfence();                       // release our atomics
        atomicAdd(cnt, 1u);
        while (__hip_atomic_load(cnt, __ATOMIC_ACQUIRE, __HIP_MEMORY_SCOPE_AGENT)
               < RBLK) {}
        sres[0] = __uint_as_float(
            __hip_atomic_load(mm + 0, __ATOMIC_RELAXED, __HIP_MEMORY_SCOPE_AGENT));
        sres[1] = __uint_as_float(
            __hip_atomic_load(mm + 1, __ATOMIC_RELAXED, __HIP_MEMORY_SCOPE_AGENT));
    }
    __syncthreads();
    out[n] = sres[1] + sres[0] - v;
}

extern "C" void kernel_launch(void* const* d_in, const int* in_sizes, int n_in,
                              void* d_out, int out_size, void* d_ws, size_t ws_size,
                              hipStream_t stream) {
    const float* samples = (const float*)d_in[0];
    const float* means   = (const float*)d_in[1];
    const float* stds    = (const float*)d_in[2];
    unsigned char* ws = (unsigned char*)d_ws;
    float* out = (float*)d_out;

    kde_fused<<<dim3(NS / 256, MSPLIT), 256, 0, stream>>>(samples, means, stds, ws);
    reduce_flip<<<dim3(RBLK), 256, 0, stream>>>(ws, out);
}